// Round 1
// 382.460 us; speedup vs baseline: 1.0138x; 1.0138x over previous
//
#include <hip/hip_runtime.h>
#include <hip/hip_bf16.h>
#include <math.h>

#define TOKENS 32768
#define DIM    2048
#define NEXP   64
#define TOPK   6

#define BM   64
#define BK   64
#define NIT  (DIM / BK)            // 32 K-chunks
#define PL_SH   (NEXP * BK)        // 4096 shorts per plane per chunk (8192 B)
#define CH_SH   (3 * PL_SH)        // 12288 shorts per chunk (h,m,l planes)
#define CH_B    (CH_SH * 2)        // 24576 bytes per chunk

typedef float f32x4 __attribute__((ext_vector_type(4)));
typedef short sh8  __attribute__((ext_vector_type(8)));

__device__ __forceinline__ ushort f2bf(float f) {
    union { __hip_bfloat16 b; ushort u; } c;
    c.b = __float2bfloat16(f);
    return c.u;
}
__device__ __forceinline__ float bf2f(ushort u) {
    union { ushort u; __hip_bfloat16 b; } c;
    c.u = u;
    return __bfloat162float(c.b);
}

// async global->LDS, 16 B per lane, linear dest (wave-uniform base + lane*16)
#define GLDS(gp, lp) __builtin_amdgcn_global_load_lds( \
    (const __attribute__((address_space(1))) void*)(gp), \
    (__attribute__((address_space(3))) void*)(lp), 16, 0, 0)

// ---------------------------------------------------------------------------
// Pre-kernel: split w (64x2048 fp32) into 3 bf16 planes ONCE, laid out as the
// exact byte image the main kernel stages per chunk, with the 16B-group XOR
// swizzle pre-applied to the SOURCE (rule #21: linear gl_lds dest + inverse-
// swizzled source + swizzled ds_read).
// ws image, per chunk it: [plane P][expert e][group g] 16B where group g holds
// k = it*64 + (g ^ (e&7))*8 .. +8.
// ---------------------------------------------------------------------------
__global__ void wsplit_kernel(const float* __restrict__ w, short* __restrict__ ws)
{
    const int idx = blockIdx.x * 256 + threadIdx.x;   // 32*64*8 = 16384 threads
    const int g  = idx & 7;
    const int e  = (idx >> 3) & 63;
    const int it = idx >> 9;                          // 0..31
    const int c  = g ^ (e & 7);

    const float* src = w + (long)e * DIM + it * BK + c * 8;
    float4 f0 = *(const float4*)(src);
    float4 f1 = *(const float4*)(src + 4);

    sh8 h, m, l;
#pragma unroll
    for (int i = 0; i < 8; ++i) {
        float f = (i < 4) ? ((const float*)&f0)[i] : ((const float*)&f1)[i - 4];
        ushort hh = f2bf(f);  float r1 = f - bf2f(hh);
        ushort mm = f2bf(r1); float r2 = r1 - bf2f(mm);
        ushort ll = f2bf(r2);
        h[i] = (short)hh; m[i] = (short)mm; l[i] = (short)ll;
    }
    short* dst = ws + (long)it * CH_SH + e * BK + g * 8;
    *(sh8*)(dst)              = h;
    *(sh8*)(dst + PL_SH)      = m;
    *(sh8*)(dst + 2 * PL_SH)  = l;
}

// ---------------------------------------------------------------------------
// Main kernel: A (x) lives in registers (per-lane fragment loads + in-reg
// 3-way split); B (w planes) staged bf16 via global_load_lds, double-buffered,
// ONE barrier per chunk. 6-product split MFMA identical to previous version.
// ---------------------------------------------------------------------------
__global__ __launch_bounds__(256, 2)
void gate_kernel(const float* __restrict__ x,
                 const short* __restrict__ ws,
                 const float* __restrict__ bias,
                 float* __restrict__ out)
{
    __shared__ __align__(16) short smem[2 * CH_SH];   // 49152 B (2 B-chunk buffers)

    const int tid  = threadIdx.x;
    const int wave = tid >> 6;
    const int lane = tid & 63;
    const int quad = lane >> 4;
    const int l15  = lane & 15;
    const int tok0 = blockIdx.x * BM;

    // A fragment source: lane owns token row (wave*16+l15), k base quad*8
    const float* xg = x + (long)(tok0 + wave * 16 + l15) * DIM + quad * 8;

    // B ds_read byte bases (per ks); swizzle folded into the register once:
    // addr = l15*128 + ((ks*4+quad) ^ (l15&7))*16  (+ imm: nt*2048 + plane*8192 + buf*24576)
    const int h8  = l15 & 7;
    const int vb0 = l15 * 128 + (((0 * 4 + quad) ^ h8) << 4);
    const int vb1 = l15 * 128 + (((1 * 4 + quad) ^ h8) << 4);
    const char* sb = (const char*)smem;

    f32x4 acc[4];
#pragma unroll
    for (int nt = 0; nt < 4; ++nt) acc[nt] = (f32x4){0.f, 0.f, 0.f, 0.f};

    auto stage = [&](int it, int bp) {              // 6 x global_load_lds dwordx4
        const short* s = ws + (long)it * CH_SH + tid * 8;
        short* d = smem + bp * CH_SH + tid * 8;
#pragma unroll
        for (int j = 0; j < 6; ++j) GLDS(s + j * 2048, d + j * 2048);
    };

    float4 fA[4], fB[4];                            // A fp32 staging regs (2 chunks)
    auto loadA = [&](float4* f, int it) {
        const float* p = xg + it * BK;
        f[0] = *(const float4*)(p);
        f[1] = *(const float4*)(p + 4);
        f[2] = *(const float4*)(p + 32);
        f[3] = *(const float4*)(p + 36);
    };

    sh8 fr[2][3];                                   // per-ks A fragments h,m,l
    auto convert = [&](const float4* f) {
#pragma unroll
        for (int ks = 0; ks < 2; ++ks) {
            sh8 h, m, l;
#pragma unroll
            for (int i = 0; i < 8; ++i) {
                float v = ((const float*)&f[ks * 2])[i];
                ushort hh = f2bf(v);  float r1 = v - bf2f(hh);
                ushort mm = f2bf(r1); float r2 = r1 - bf2f(mm);
                h[i] = (short)hh; m[i] = (short)mm; l[i] = (short)f2bf(r2);
            }
            fr[ks][0] = h; fr[ks][1] = m; fr[ks][2] = l;
        }
    };

    auto compute = [&](int bufbyte) {
#pragma unroll
        for (int ks = 0; ks < 2; ++ks) {
            const int va = (ks ? vb1 : vb0) + bufbyte;
#pragma unroll
            for (int nt = 0; nt < 4; ++nt) {
                const int ro = va + nt * 2048;
                sh8 bh = *(const sh8*)(sb + ro);
                sh8 bm = *(const sh8*)(sb + ro + 8192);
                sh8 bl = *(const sh8*)(sb + ro + 16384);
                acc[nt] = __builtin_amdgcn_mfma_f32_16x16x32_bf16(fr[ks][0], bh, acc[nt], 0, 0, 0); // hh
                acc[nt] = __builtin_amdgcn_mfma_f32_16x16x32_bf16(fr[ks][1], bh, acc[nt], 0, 0, 0); // mh
                acc[nt] = __builtin_amdgcn_mfma_f32_16x16x32_bf16(fr[ks][0], bm, acc[nt], 0, 0, 0); // hm
                acc[nt] = __builtin_amdgcn_mfma_f32_16x16x32_bf16(fr[ks][2], bh, acc[nt], 0, 0, 0); // lh
                acc[nt] = __builtin_amdgcn_mfma_f32_16x16x32_bf16(fr[ks][1], bm, acc[nt], 0, 0, 0); // mm
                acc[nt] = __builtin_amdgcn_mfma_f32_16x16x32_bf16(fr[ks][0], bl, acc[nt], 0, 0, 0); // hl
            }
        }
    };

    // prologue: B(0) staged, A(0) and A(1) in flight; barrier drains all
    stage(0, 0);
    loadA(fA, 0);
    loadA(fB, 1);
    __syncthreads();

#pragma unroll 1
    for (int it = 0; it < NIT; it += 2) {
        // even half: compute buf0 / fA
        stage(it + 1, 1);                   // it+1 <= 31 always
        convert(fA);
        if (it + 2 < NIT) loadA(fA, it + 2);
        compute(0);
        __syncthreads();                    // drains B(it+1) (issued ~full half earlier)

        // odd half: compute buf1 / fB
        if (it + 2 < NIT) stage(it + 2, 0);
        convert(fB);
        if (it + 3 < NIT) loadA(fB, it + 3);
        compute(CH_B);
        __syncthreads();
    }

    // ---- logits -> red LDS (stride 69 floats keeps lanes conflict-free) ----
    float* red = (float*)smem;              // 64 x 69 x 4 B = 17664 B, overlays buf0
#pragma unroll
    for (int nt = 0; nt < 4; ++nt)
#pragma unroll
        for (int j = 0; j < 4; ++j) {
            const int row = wave * 16 + quad * 4 + j;   // token (C/D row = quad*4+reg)
            const int col = nt * 16 + l15;              // expert (C/D col = lane&15)
            red[row * 69 + col] = acc[nt][j];
        }
    __syncthreads();

    // ---- wave-parallel epilogue: 4 lanes per token, 16 experts per lane ----
    {
        const int t = lane >> 2;            // token within this wave's 16
        const int s = lane & 3;             // expert quarter
        const int row = wave * 16 + t;

        float lg[16];
#pragma unroll
        for (int i = 0; i < 16; ++i) lg[i] = red[row * 69 + s * 16 + i];

        float mx = lg[0];
#pragma unroll
        for (int i = 1; i < 16; ++i) mx = fmaxf(mx, lg[i]);
        mx = fmaxf(mx, __shfl_xor(mx, 1));
        mx = fmaxf(mx, __shfl_xor(mx, 2));

        float sum = 0.f;
#pragma unroll
        for (int i = 0; i < 16; ++i) { lg[i] = __expf(lg[i] - mx); sum += lg[i]; }
        sum += __shfl_xor(sum, 1);
        sum += __shfl_xor(sum, 2);
        const float inv = 1.0f / sum;

        float sc[16], bz[16];
#pragma unroll
        for (int i = 0; i < 16; ++i) {
            sc[i] = lg[i] * inv;                        // returned weight
            bz[i] = sc[i] + bias[s * 16 + i];           // selection score
        }

        const int tok = tok0 + wave * 16 + t;
        float* wout = out + (long)tok * TOPK;
        float* iout = out + (long)TOKENS * TOPK + (long)tok * TOPK;

        unsigned used = 0;
#pragma unroll
        for (int p = 0; p < TOPK; ++p) {
            float bv = -INFINITY; int bi = 1 << 20; float bw = 0.f;
#pragma unroll
            for (int i = 0; i < 16; ++i) {
                float v = ((used >> i) & 1u) ? -INFINITY : bz[i];
                if (v > bv) { bv = v; bi = s * 16 + i; bw = sc[i]; } // strict > = lower-index tie-break
            }
#pragma unroll
            for (int d = 1; d < 4; d <<= 1) {           // 4-lane argmax, ties -> lower idx
                float ov = __shfl_xor(bv, d);
                int   oi = __shfl_xor(bi, d);
                float ow = __shfl_xor(bw, d);
                if (ov > bv || (ov == bv && oi < bi)) { bv = ov; bi = oi; bw = ow; }
            }
            if ((bi >> 4) == s) used |= 1u << (bi & 15);
            if (s == 0) { wout[p] = bw; iout[p] = (float)bi; }  // ROUTE_SCALE == 1.0
        }
    }
}

extern "C" void kernel_launch(void* const* d_in, const int* in_sizes, int n_in,
                              void* d_out, int out_size, void* d_ws, size_t ws_size,
                              hipStream_t stream) {
    const float* x = (const float*)d_in[0];
    const float* w = (const float*)d_in[1];
    const float* b = (const float*)d_in[2];
    float* out = (float*)d_out;
    short* ws = (short*)d_ws;                 // needs 32*24576 = 786432 B

    wsplit_kernel<<<dim3(64), dim3(256), 0, stream>>>(w, ws);
    gate_kernel<<<dim3(TOKENS / BM), dim3(256), 0, stream>>>(x, ws, b, out);
}